// Round 1
// baseline (14119.208 us; speedup 1.0000x reference)
//
#include <hip/hip_runtime.h>

#define NN 32768
#define NEDGE 400000
#define HH 128
#define OUTC 64

// ---------------- gather: x[i] = emb[idx[i]] ----------------
__global__ __launch_bounds__(256) void gather_emb(const int* __restrict__ idx,
    const float* __restrict__ emb, float* __restrict__ x)
{
    int gid = blockIdx.x * blockDim.x + threadIdx.x;   // one float4 per thread
    int row = gid >> 5;                                // H/4 = 32 float4 per row
    int col = gid & 31;
    if (row >= NN) return;
    ((float4*)x)[gid] = ((const float4*)(emb + (size_t)idx[row] * HH))[col];
}

// ---------------- scatter-sum: m[d] += relu?(x[s]), cnt[d] += 1 ----------------
__global__ __launch_bounds__(256) void scatter_sum(const int* __restrict__ si,
    const int* __restrict__ di, const float* __restrict__ xsrc,
    float* __restrict__ m, float* __restrict__ cnt, int applyRelu)
{
    int gid = blockIdx.x * blockDim.x + threadIdx.x;
    int edge = gid >> 5;            // 32 lanes per edge, float4 each
    int lane = gid & 31;
    if (edge >= NEDGE) return;
    int s = si[edge];
    int d = di[edge];
    float4 v = ((const float4*)(xsrc + (size_t)s * HH))[lane];
    if (applyRelu) {
        v.x = fmaxf(v.x, 0.0f); v.y = fmaxf(v.y, 0.0f);
        v.z = fmaxf(v.z, 0.0f); v.w = fmaxf(v.w, 0.0f);
    }
    float* dst = m + (size_t)d * HH + lane * 4;
    atomicAdd(dst + 0, v.x);
    atomicAdd(dst + 1, v.y);
    atomicAdd(dst + 2, v.z);
    atomicAdd(dst + 3, v.w);
    if (lane == 0) atomicAdd(cnt + d, 1.0f);
}

// ------- fused: o = (m*invcnt)@Wl + bl + relu?(x)@Wr ; acc += l2norm(o) -------
__global__ __launch_bounds__(128) void gemm_norm_acc(
    const float* __restrict__ m, const float* __restrict__ cnt,
    const float* __restrict__ xdst, const float* __restrict__ Wl,
    const float* __restrict__ bl, const float* __restrict__ Wr,
    float* __restrict__ acc, int applyRelu)
{
    __shared__ float wls[32][HH];
    __shared__ float wrs[32][HH];
    __shared__ float ms[8][HH];
    __shared__ float xs[8][HH];
    __shared__ float wsum[2][8];
    int tid = threadIdx.x;
    size_t r0 = (size_t)blockIdx.x * 8;

    #pragma unroll
    for (int r = 0; r < 8; ++r) {
        float c = cnt[r0 + r];
        float inv = 1.0f / fmaxf(c, 1.0f);
        ms[r][tid] = m[(r0 + r) * HH + tid] * inv;
        float xv = xdst[(r0 + r) * HH + tid];
        xs[r][tid] = applyRelu ? fmaxf(xv, 0.0f) : xv;
    }

    float o[8];
    float b = bl[tid];
    #pragma unroll
    for (int r = 0; r < 8; ++r) o[r] = b;

    for (int k0 = 0; k0 < HH; k0 += 32) {
        __syncthreads();   // also makes ms/xs visible on first iteration
        #pragma unroll
        for (int kk = 0; kk < 32; ++kk) {
            wls[kk][tid] = Wl[(size_t)(k0 + kk) * HH + tid];
            wrs[kk][tid] = Wr[(size_t)(k0 + kk) * HH + tid];
        }
        __syncthreads();
        #pragma unroll
        for (int kk = 0; kk < 32; ++kk) {
            float wl = wls[kk][tid];
            float wr = wrs[kk][tid];
            #pragma unroll
            for (int r = 0; r < 8; ++r)
                o[r] += ms[r][k0 + kk] * wl + xs[r][k0 + kk] * wr;
        }
    }

    // row L2 norms: reduce o[r]^2 across the 128 threads (2 waves)
    #pragma unroll
    for (int r = 0; r < 8; ++r) {
        float v = o[r] * o[r];
        v += __shfl_down(v, 32);
        v += __shfl_down(v, 16);
        v += __shfl_down(v, 8);
        v += __shfl_down(v, 4);
        v += __shfl_down(v, 2);
        v += __shfl_down(v, 1);
        if ((tid & 63) == 0) wsum[tid >> 6][r] = v;
    }
    __syncthreads();
    #pragma unroll
    for (int r = 0; r < 8; ++r) {
        float ss = wsum[0][r] + wsum[1][r];
        float scale = 1.0f / fmaxf(sqrtf(ss), 1e-12f);
        acc[(r0 + r) * HH + tid] += o[r] * scale;
    }
}

// ---------------- head: out = relu(x_reaction) @ W_out + b_out ----------------
__global__ __launch_bounds__(256) void out_gemm(const float* __restrict__ x,
    const float* __restrict__ W, const float* __restrict__ b, float* __restrict__ out)
{
    __shared__ float wsm[HH][OUTC];
    int tid = threadIdx.x;
    for (int i = tid; i < HH * OUTC; i += 256) wsm[i >> 6][i & 63] = W[i];
    __syncthreads();
    int j = tid & 63;
    int rq = tid >> 6;
    size_t r0 = (size_t)blockIdx.x * 16;
    float bj = b[j];
    #pragma unroll
    for (int i = 0; i < 4; ++i) {
        size_t row = r0 + rq * 4 + i;
        const float* xr = x + row * HH;
        float o = bj;
        #pragma unroll 8
        for (int k = 0; k < HH; ++k) o += fmaxf(xr[k], 0.0f) * wsm[k][j];
        out[row * OUTC + j] = o;
    }
}

extern "C" void kernel_launch(void* const* d_in, const int* in_sizes, int n_in,
                              void* d_out, int out_size, void* d_ws, size_t ws_size,
                              hipStream_t stream) {
    const int*   x_protein  = (const int*)d_in[0];
    const int*   x_molecule = (const int*)d_in[1];
    const int*   x_reaction = (const int*)d_in[2];
    const int*   x_complex  = (const int*)d_in[3];
    const int*   ei         = (const int*)d_in[4];   // (8, 2, NEDGE)
    const float* emb_p      = (const float*)d_in[5];
    const float* emb_m      = (const float*)d_in[6];
    const float* emb_r      = (const float*)d_in[7]; // (1,H)
    const float* emb_c      = (const float*)d_in[8]; // (1,H)
    const float* Wl         = (const float*)d_in[9];  // (2,8,H,H)
    const float* bl         = (const float*)d_in[10]; // (2,8,H)
    const float* Wr         = (const float*)d_in[11]; // (2,8,H,H)
    const float* W_out      = (const float*)d_in[12]; // (H,64)
    const float* b_out      = (const float*)d_in[13]; // (64)
    float* out = (float*)d_out;

    const size_t NH = (size_t)NN * HH;
    float* A   = (float*)d_ws;        // x buffers, 4 types
    float* B   = A + 4 * NH;          // acc/x ping-pong
    float* m   = A + 8 * NH;          // scatter-sum buffer
    float* cnt = A + 9 * NH;          // counts (N floats), contiguous after m

    // type ids: 0=protein 1=molecule 2=reaction 3=complex
    static const int SRC[8] = {0, 1, 3, 0, 1, 2, 2, 3};
    static const int DST[8] = {2, 2, 2, 3, 3, 0, 1, 0};

    // initial embeddings -> A
    gather_emb<<<4096, 256, 0, stream>>>(x_protein,  emb_p, A + 0 * NH);
    gather_emb<<<4096, 256, 0, stream>>>(x_molecule, emb_m, A + 1 * NH);
    gather_emb<<<4096, 256, 0, stream>>>(x_reaction, emb_r, A + 2 * NH);
    gather_emb<<<4096, 256, 0, stream>>>(x_complex,  emb_c, A + 3 * NH);

    for (int l = 0; l < 2; ++l) {
        float* X   = (l == 0) ? A : B;
        float* ACC = (l == 0) ? B : A;
        int relu = (l > 0) ? 1 : 0;
        hipMemsetAsync(ACC, 0, 4 * NH * sizeof(float), stream);
        for (int e = 0; e < 8; ++e) {
            hipMemsetAsync(m, 0, (NH + NN) * sizeof(float), stream); // m + cnt
            const int* si = ei + ((size_t)e * 2 + 0) * NEDGE;
            const int* di = ei + ((size_t)e * 2 + 1) * NEDGE;
            scatter_sum<<<50000, 256, 0, stream>>>(si, di, X + (size_t)SRC[e] * NH,
                                                   m, cnt, relu);
            size_t w_off = (size_t)(l * 8 + e) * HH * HH;
            size_t b_off = (size_t)(l * 8 + e) * HH;
            gemm_norm_acc<<<4096, 128, 0, stream>>>(m, cnt, X + (size_t)DST[e] * NH,
                                                    Wl + w_off, bl + b_off, Wr + w_off,
                                                    ACC + (size_t)DST[e] * NH, relu);
        }
    }
    // after layer 1, x lives in A (acc of layer 1); reaction = type 2
    out_gemm<<<2048, 256, 0, stream>>>(A + 2 * NH, W_out, b_out, out);
}

// Round 2
// 3949.786 us; speedup vs baseline: 3.5747x; 3.5747x over previous
//
#include <hip/hip_runtime.h>

#define NN 32768
#define NEDGE 400000
#define HH 128
#define OUTC 64

// ---------------- gather: x[i] = emb[idx[i]] ----------------
__global__ __launch_bounds__(256) void gather_emb(const int* __restrict__ idx,
    const float* __restrict__ emb, float* __restrict__ x)
{
    int gid = blockIdx.x * blockDim.x + threadIdx.x;   // one float4 per thread
    int row = gid >> 5;                                // H/4 = 32 float4 per row
    int col = gid & 31;
    if (row >= NN) return;
    ((float4*)x)[gid] = ((const float4*)(emb + (size_t)idx[row] * HH))[col];
}

// ---------------- CSR build ----------------
__global__ __launch_bounds__(256) void hist_kernel(const int* __restrict__ di,
    int* __restrict__ cnts)
{
    int e = blockIdx.x * blockDim.x + threadIdx.x;
    if (e >= NEDGE) return;
    atomicAdd(&cnts[di[e]], 1);
}

// single block, 1024 threads, 32 elements each: exclusive scan of NN counts.
// data: counts in, exclusive bases out (doubles as fill cursor). rowptr: bases + total.
__global__ __launch_bounds__(1024) void scan_block(int* __restrict__ data,
    int* __restrict__ rowptr)
{
    __shared__ int part[1024];
    int t = threadIdx.x;
    int base = t * 32;
    int c[32];
    int run = 0;
    #pragma unroll
    for (int i = 0; i < 32; ++i) { int v = data[base + i]; c[i] = run; run += v; }
    part[t] = run;
    __syncthreads();
    for (int off = 1; off < 1024; off <<= 1) {
        int v = (t >= off) ? part[t - off] : 0;
        __syncthreads();
        part[t] += v;
        __syncthreads();
    }
    int excl = part[t] - run;
    #pragma unroll
    for (int i = 0; i < 32; ++i) {
        int b = excl + c[i];
        data[base + i]   = b;
        rowptr[base + i] = b;
    }
    if (t == 1023) rowptr[NN] = part[1023];
}

__global__ __launch_bounds__(256) void fill_csr(const int* __restrict__ si,
    const int* __restrict__ di, int* __restrict__ cursor, int* __restrict__ srcs)
{
    int e = blockIdx.x * blockDim.x + threadIdx.x;
    if (e >= NEDGE) return;
    int p = atomicAdd(&cursor[di[e]], 1);
    srcs[p] = si[e];
}

// ---------------- pull aggregation: m[d] = mean over in-edges of relu?(x[s]) ----
__global__ __launch_bounds__(256) void csr_mean(const int* __restrict__ rowptr,
    const int* __restrict__ srcs, const float* __restrict__ xsrc,
    float* __restrict__ m, int applyRelu)
{
    int row  = (blockIdx.x * 256 + threadIdx.x) >> 6;  // one wave per dst row
    int lane = threadIdx.x & 63;
    if (row >= NN) return;
    int beg = rowptr[row], end = rowptr[row + 1];
    const float2* xp = (const float2*)xsrc;
    float2 a0 = make_float2(0.f, 0.f), a1 = make_float2(0.f, 0.f);
    int j = beg;
    for (; j + 2 <= end; j += 2) {
        int s0 = srcs[j], s1 = srcs[j + 1];
        float2 v0 = xp[(size_t)s0 * 64 + lane];
        float2 v1 = xp[(size_t)s1 * 64 + lane];
        if (applyRelu) {
            v0.x = fmaxf(v0.x, 0.f); v0.y = fmaxf(v0.y, 0.f);
            v1.x = fmaxf(v1.x, 0.f); v1.y = fmaxf(v1.y, 0.f);
        }
        a0.x += v0.x; a0.y += v0.y;
        a1.x += v1.x; a1.y += v1.y;
    }
    if (j < end) {
        int s0 = srcs[j];
        float2 v0 = xp[(size_t)s0 * 64 + lane];
        if (applyRelu) { v0.x = fmaxf(v0.x, 0.f); v0.y = fmaxf(v0.y, 0.f); }
        a0.x += v0.x; a0.y += v0.y;
    }
    float inv = 1.0f / fmaxf((float)(end - beg), 1.0f);
    ((float2*)m)[(size_t)row * 64 + lane] =
        make_float2((a0.x + a1.x) * inv, (a0.y + a1.y) * inv);
}

// ------- fused: o = m@Wl + bl + relu?(x)@Wr ; acc (=|+=) l2norm(o) -------
__global__ __launch_bounds__(128) void gemm_norm_acc(
    const float* __restrict__ m, const float* __restrict__ xdst,
    const float* __restrict__ Wl, const float* __restrict__ bl,
    const float* __restrict__ Wr, float* __restrict__ acc,
    int applyRelu, int accumulate)
{
    __shared__ float wls[32][HH];
    __shared__ float wrs[32][HH];
    __shared__ float ms[8][HH];
    __shared__ float xs[8][HH];
    __shared__ float wsum[2][8];
    int tid = threadIdx.x;
    size_t r0 = (size_t)blockIdx.x * 8;

    #pragma unroll
    for (int r = 0; r < 8; ++r) {
        ms[r][tid] = m[(r0 + r) * HH + tid];
        float xv = xdst[(r0 + r) * HH + tid];
        xs[r][tid] = applyRelu ? fmaxf(xv, 0.0f) : xv;
    }

    float o[8];
    float b = bl[tid];
    #pragma unroll
    for (int r = 0; r < 8; ++r) o[r] = b;

    for (int k0 = 0; k0 < HH; k0 += 32) {
        __syncthreads();   // also makes ms/xs visible on first iteration
        #pragma unroll
        for (int kk = 0; kk < 32; ++kk) {
            wls[kk][tid] = Wl[(size_t)(k0 + kk) * HH + tid];
            wrs[kk][tid] = Wr[(size_t)(k0 + kk) * HH + tid];
        }
        __syncthreads();
        #pragma unroll
        for (int kk = 0; kk < 32; ++kk) {
            float wl = wls[kk][tid];
            float wr = wrs[kk][tid];
            #pragma unroll
            for (int r = 0; r < 8; ++r)
                o[r] += ms[r][k0 + kk] * wl + xs[r][k0 + kk] * wr;
        }
    }

    // row L2 norms: reduce o[r]^2 across the 128 threads (2 waves)
    #pragma unroll
    for (int r = 0; r < 8; ++r) {
        float v = o[r] * o[r];
        v += __shfl_down(v, 32);
        v += __shfl_down(v, 16);
        v += __shfl_down(v, 8);
        v += __shfl_down(v, 4);
        v += __shfl_down(v, 2);
        v += __shfl_down(v, 1);
        if ((tid & 63) == 0) wsum[tid >> 6][r] = v;
    }
    __syncthreads();
    #pragma unroll
    for (int r = 0; r < 8; ++r) {
        float ss = wsum[0][r] + wsum[1][r];
        float scale = 1.0f / fmaxf(sqrtf(ss), 1e-12f);
        size_t o_idx = (r0 + r) * HH + tid;
        float val = o[r] * scale;
        acc[o_idx] = accumulate ? (acc[o_idx] + val) : val;
    }
}

// ---------------- head: out = relu(x_reaction) @ W_out + b_out ----------------
__global__ __launch_bounds__(256) void out_gemm(const float* __restrict__ x,
    const float* __restrict__ W, const float* __restrict__ b, float* __restrict__ out)
{
    __shared__ float wsm[HH][OUTC];
    int tid = threadIdx.x;
    for (int i = tid; i < HH * OUTC; i += 256) wsm[i >> 6][i & 63] = W[i];
    __syncthreads();
    int j = tid & 63;
    int rq = tid >> 6;
    size_t r0 = (size_t)blockIdx.x * 16;
    float bj = b[j];
    #pragma unroll
    for (int i = 0; i < 4; ++i) {
        size_t row = r0 + rq * 4 + i;
        const float* xr = x + row * HH;
        float o = bj;
        #pragma unroll 8
        for (int k = 0; k < HH; ++k) o += fmaxf(xr[k], 0.0f) * wsm[k][j];
        out[row * OUTC + j] = o;
    }
}

extern "C" void kernel_launch(void* const* d_in, const int* in_sizes, int n_in,
                              void* d_out, int out_size, void* d_ws, size_t ws_size,
                              hipStream_t stream) {
    const int*   x_protein  = (const int*)d_in[0];
    const int*   x_molecule = (const int*)d_in[1];
    const int*   x_reaction = (const int*)d_in[2];
    const int*   x_complex  = (const int*)d_in[3];
    const int*   ei         = (const int*)d_in[4];   // (8, 2, NEDGE)
    const float* emb_p      = (const float*)d_in[5];
    const float* emb_m      = (const float*)d_in[6];
    const float* emb_r      = (const float*)d_in[7]; // (1,H)
    const float* emb_c      = (const float*)d_in[8]; // (1,H)
    const float* Wl         = (const float*)d_in[9];  // (2,8,H,H)
    const float* bl         = (const float*)d_in[10]; // (2,8,H)
    const float* Wr         = (const float*)d_in[11]; // (2,8,H,H)
    const float* W_out      = (const float*)d_in[12]; // (H,64)
    const float* b_out      = (const float*)d_in[13]; // (64)
    float* out = (float*)d_out;

    const size_t NH = (size_t)NN * HH;
    float* A = (float*)d_ws;          // x buffers, 4 types
    float* B = A + 4 * NH;            // acc/x ping-pong
    float* m = A + 8 * NH;            // aggregation buffer
    int* rowptr_all = (int*)(A + 9 * NH);          // 8 * (NN+1)
    int* srcs_all   = rowptr_all + 8 * (NN + 1);   // 8 * NEDGE
    int* cursor     = srcs_all + 8 * (size_t)NEDGE; // NN (counts -> bases -> cursor)

    // type ids: 0=protein 1=molecule 2=reaction 3=complex
    static const int SRC[8] = {0, 1, 3, 0, 1, 2, 2, 3};
    static const int DST[8] = {2, 2, 2, 3, 3, 0, 1, 0};
    // first edge type writing each dst (write vs accumulate)
    static const int ACCF[8] = {0, 1, 1, 0, 1, 0, 0, 1};

    // ---- build CSR per edge type (reused by both layers) ----
    for (int e = 0; e < 8; ++e) {
        const int* si = ei + ((size_t)e * 2 + 0) * NEDGE;
        const int* di = ei + ((size_t)e * 2 + 1) * NEDGE;
        int* rowptr = rowptr_all + (size_t)e * (NN + 1);
        int* srcs   = srcs_all + (size_t)e * NEDGE;
        hipMemsetAsync(cursor, 0, NN * sizeof(int), stream);
        hist_kernel<<<(NEDGE + 255) / 256, 256, 0, stream>>>(di, cursor);
        scan_block<<<1, 1024, 0, stream>>>(cursor, rowptr);
        fill_csr<<<(NEDGE + 255) / 256, 256, 0, stream>>>(si, di, cursor, srcs);
    }

    // ---- initial embeddings -> A ----
    gather_emb<<<4096, 256, 0, stream>>>(x_protein,  emb_p, A + 0 * NH);
    gather_emb<<<4096, 256, 0, stream>>>(x_molecule, emb_m, A + 1 * NH);
    gather_emb<<<4096, 256, 0, stream>>>(x_reaction, emb_r, A + 2 * NH);
    gather_emb<<<4096, 256, 0, stream>>>(x_complex,  emb_c, A + 3 * NH);

    for (int l = 0; l < 2; ++l) {
        float* X   = (l == 0) ? A : B;
        float* ACC = (l == 0) ? B : A;
        int relu = (l > 0) ? 1 : 0;
        for (int e = 0; e < 8; ++e) {
            int* rowptr = rowptr_all + (size_t)e * (NN + 1);
            int* srcs   = srcs_all + (size_t)e * NEDGE;
            csr_mean<<<(NN / 4), 256, 0, stream>>>(rowptr, srcs,
                X + (size_t)SRC[e] * NH, m, relu);
            size_t w_off = (size_t)(l * 8 + e) * HH * HH;
            size_t b_off = (size_t)(l * 8 + e) * HH;
            gemm_norm_acc<<<4096, 128, 0, stream>>>(m, X + (size_t)DST[e] * NH,
                Wl + w_off, bl + b_off, Wr + w_off,
                ACC + (size_t)DST[e] * NH, relu, ACCF[e]);
        }
    }
    // after layer 1, x lives in A (acc of layer 1); reaction = type 2
    out_gemm<<<2048, 256, 0, stream>>>(A + 2 * NH, W_out, b_out, out);
}

// Round 3
// 1165.922 us; speedup vs baseline: 12.1099x; 3.3877x over previous
//
#include <hip/hip_runtime.h>
#include <hip/hip_fp16.h>

#define NN 32768
#define NEDGE 400000
#define HH 128
#define OUTC 64

using f16x8 = __attribute__((ext_vector_type(8))) _Float16;
using f32x4 = __attribute__((ext_vector_type(4))) float;

// ---------------- gather to fp16: x[i] = fp16(emb[idx[i]]) ----------------
__global__ __launch_bounds__(256) void gather_emb_h(const int* __restrict__ idx,
    const float* __restrict__ emb, __half* __restrict__ x)
{
    int gid = blockIdx.x * 256 + threadIdx.x;  // one float4 -> 4 halfs per thread
    int row = gid >> 5;                        // 32 chunks per row
    int col = gid & 31;
    if (row >= NN) return;
    float4 v = ((const float4*)(emb + (size_t)idx[row] * HH))[col];
    __half2 h0 = __floats2half2_rn(v.x, v.y);
    __half2 h1 = __floats2half2_rn(v.z, v.w);
    ((__half2*)x)[(size_t)gid * 2]     = h0;
    ((__half2*)x)[(size_t)gid * 2 + 1] = h1;
}

// ---------------- relu + f32->fp16 convert (acc -> next-layer x) ----------------
__global__ __launch_bounds__(256) void relu_f2h(const float* __restrict__ a,
    __half* __restrict__ x, int n4)
{
    int gid = blockIdx.x * 256 + threadIdx.x;
    if (gid >= n4) return;
    float4 v = ((const float4*)a)[gid];
    __half2 h0 = __floats2half2_rn(fmaxf(v.x, 0.f), fmaxf(v.y, 0.f));
    __half2 h1 = __floats2half2_rn(fmaxf(v.z, 0.f), fmaxf(v.w, 0.f));
    ((__half2*)x)[(size_t)gid * 2]     = h0;
    ((__half2*)x)[(size_t)gid * 2 + 1] = h1;
}

// ------------- build fused weight Bt[le][n][k] fp16, k<128: Wl, k>=128: Wr -------------
__global__ __launch_bounds__(256) void build_Bt(const float* __restrict__ Wl,
    const float* __restrict__ Wr, __half* __restrict__ Bt)
{
    int gid = blockIdx.x * 256 + threadIdx.x;   // 16*256*128 = 524288
    if (gid >= 16 * 256 * 128) return;
    int le = gid >> 15;
    int n  = (gid >> 8) & 127;
    int k  = gid & 255;
    float v = (k < 128) ? Wl[(size_t)le * 16384 + (size_t)k * 128 + n]
                        : Wr[(size_t)le * 16384 + (size_t)(k - 128) * 128 + n];
    Bt[gid] = __float2half(v);
}

// ---------------- CSR build ----------------
__global__ __launch_bounds__(256) void hist_kernel(const int* __restrict__ di,
    int* __restrict__ cnts)
{
    int e = blockIdx.x * blockDim.x + threadIdx.x;
    if (e >= NEDGE) return;
    atomicAdd(&cnts[di[e]], 1);
}

__global__ __launch_bounds__(1024) void scan_block(int* __restrict__ data,
    int* __restrict__ rowptr)
{
    __shared__ int part[1024];
    int t = threadIdx.x;
    int base = t * 32;
    int c[32];
    int run = 0;
    #pragma unroll
    for (int i = 0; i < 32; ++i) { int v = data[base + i]; c[i] = run; run += v; }
    part[t] = run;
    __syncthreads();
    for (int off = 1; off < 1024; off <<= 1) {
        int v = (t >= off) ? part[t - off] : 0;
        __syncthreads();
        part[t] += v;
        __syncthreads();
    }
    int excl = part[t] - run;
    #pragma unroll
    for (int i = 0; i < 32; ++i) {
        int b = excl + c[i];
        data[base + i]   = b;
        rowptr[base + i] = b;
    }
    if (t == 1023) rowptr[NN] = part[1023];
}

__global__ __launch_bounds__(256) void fill_csr(const int* __restrict__ si,
    const int* __restrict__ di, int* __restrict__ cursor, int* __restrict__ srcs)
{
    int e = blockIdx.x * blockDim.x + threadIdx.x;
    if (e >= NEDGE) return;
    int p = atomicAdd(&cursor[di[e]], 1);
    srcs[p] = si[e];
}

// ---------------- pull aggregation (fp16 in/out, f32 accumulate) ----------------
__global__ __launch_bounds__(256) void csr_mean_h(const int* __restrict__ rowptr,
    const int* __restrict__ srcs, const __half* __restrict__ xsrc,
    __half* __restrict__ m)
{
    int row  = (blockIdx.x * 256 + threadIdx.x) >> 6;  // one wave per dst row
    int lane = threadIdx.x & 63;
    if (row >= NN) return;
    int beg = rowptr[row], end = rowptr[row + 1];
    const uint* xp = (const uint*)xsrc;   // 2 halfs per uint, 64 uints per row
    float ax0 = 0.f, ay0 = 0.f, ax1 = 0.f, ay1 = 0.f;
    int j = beg;
    for (; j + 2 <= end; j += 2) {
        int s0 = srcs[j], s1 = srcs[j + 1];
        uint v0 = xp[(size_t)s0 * 64 + lane];
        uint v1 = xp[(size_t)s1 * 64 + lane];
        float2 f0 = __half22float2(*(__half2*)&v0);
        float2 f1 = __half22float2(*(__half2*)&v1);
        ax0 += f0.x; ay0 += f0.y;
        ax1 += f1.x; ay1 += f1.y;
    }
    if (j < end) {
        int s0 = srcs[j];
        uint v0 = xp[(size_t)s0 * 64 + lane];
        float2 f0 = __half22float2(*(__half2*)&v0);
        ax0 += f0.x; ay0 += f0.y;
    }
    float inv = 1.0f / fmaxf((float)(end - beg), 1.0f);
    __half2 h = __floats2half2_rn((ax0 + ax1) * inv, (ay0 + ay1) * inv);
    ((__half2*)m)[(size_t)row * 64 + lane] = h;
}

// ------- layer-0 shortcut when all source rows are identical: m = cnt>0 ? row : 0 -------
__global__ __launch_bounds__(256) void const_mean_h(const int* __restrict__ rowptr,
    const uint* __restrict__ rowsrc, uint* __restrict__ m)
{
    int gid = blockIdx.x * 256 + threadIdx.x;
    int row = gid >> 6, c = gid & 63;
    if (row >= NN) return;
    bool has = rowptr[row + 1] > rowptr[row];
    m[(size_t)row * 64 + c] = has ? rowsrc[c] : 0u;
}

// ------- MFMA GEMM: o = [m | x] @ Bt^T + bl ; acc (=|+=) l2norm(o) -------
// Bt layout: [n=128][k=256] fp16. Block: 128 rows, 4 waves x (32 rows x 128 cols).
__global__ __launch_bounds__(256) void gemm_mfma(
    const __half* __restrict__ mh, const __half* __restrict__ xh,
    const __half* __restrict__ Bt, const float* __restrict__ bl,
    float* __restrict__ accg, int accumulate)
{
    __shared__ __half As[128][40];   // 32 halfs + 8 pad -> 80B row stride (conflict-free b128)
    __shared__ __half Bs[128][40];
    int tid  = threadIdx.x;
    int lane = tid & 63;
    int wave = tid >> 6;             // rows [wave*32, wave*32+32)
    size_t r0 = (size_t)blockIdx.x * 128;

    f32x4 acc[2][8];
    #pragma unroll
    for (int nf = 0; nf < 8; ++nf) {
        float bv = bl[(lane & 15) + nf * 16];
        #pragma unroll
        for (int mf = 0; mf < 2; ++mf) acc[mf][nf] = (f32x4){bv, bv, bv, bv};
    }

    const int arow = wave * 32 + (lane & 15);
    const int kof  = (lane >> 4) * 8;
    const int row0 = tid >> 1;                 // load slots: 2 chunks/thread
    // slot s in [0,512): row = s>>2, chunk c = s&3 (16B each)
    const int ra = tid >> 2,        ca = tid & 3;          // slot tid
    const int rb = (tid + 256) >> 2, cb = (tid + 256) & 3; // slot tid+256
    (void)row0;

    for (int ks = 0; ks < 8; ++ks) {
        int k0 = ks * 32;
        const __half* Asrc = (k0 < 128) ? (mh + k0) : (xh + (k0 - 128));
        __syncthreads();
        uint4 a0 = *(const uint4*)(Asrc + (r0 + ra) * HH + ca * 8);
        uint4 a1 = *(const uint4*)(Asrc + (r0 + rb) * HH + cb * 8);
        uint4 b0 = *(const uint4*)(Bt + (size_t)ra * 256 + k0 + ca * 8);
        uint4 b1 = *(const uint4*)(Bt + (size_t)rb * 256 + k0 + cb * 8);
        *(uint4*)&As[ra][ca * 8] = a0;
        *(uint4*)&As[rb][cb * 8] = a1;
        *(uint4*)&Bs[ra][ca * 8] = b0;
        *(uint4*)&Bs[rb][cb * 8] = b1;
        __syncthreads();
        f16x8 af[2], bf[8];
        #pragma unroll
        for (int mf = 0; mf < 2; ++mf)
            af[mf] = *(const f16x8*)&As[arow + mf * 16][kof];
        #pragma unroll
        for (int nf = 0; nf < 8; ++nf)
            bf[nf] = *(const f16x8*)&Bs[nf * 16 + (lane & 15)][kof];
        #pragma unroll
        for (int mf = 0; mf < 2; ++mf)
            #pragma unroll
            for (int nf = 0; nf < 8; ++nf)
                acc[mf][nf] = __builtin_amdgcn_mfma_f32_16x16x32_f16(
                    af[mf], bf[nf], acc[mf][nf], 0, 0, 0);
    }

    int g = lane >> 4;
    #pragma unroll
    for (int mf = 0; mf < 2; ++mf) {
        #pragma unroll
        for (int r = 0; r < 4; ++r) {
            float s = 0.f;
            #pragma unroll
            for (int nf = 0; nf < 8; ++nf) { float v = acc[mf][nf][r]; s += v * v; }
            s += __shfl_xor(s, 1);
            s += __shfl_xor(s, 2);
            s += __shfl_xor(s, 4);
            s += __shfl_xor(s, 8);
            float scale = 1.0f / fmaxf(sqrtf(s), 1e-12f);
            size_t row = r0 + wave * 32 + mf * 16 + g * 4 + r;
            float* dst = accg + row * HH + (lane & 15);
            #pragma unroll
            for (int nf = 0; nf < 8; ++nf) {
                float val = acc[mf][nf][r] * scale;
                if (accumulate) dst[nf * 16] += val; else dst[nf * 16] = val;
            }
        }
    }
}

// ---------------- head: out = relu(x_reaction) @ W_out + b_out ----------------
__global__ __launch_bounds__(256) void out_gemm(const float* __restrict__ x,
    const float* __restrict__ W, const float* __restrict__ b, float* __restrict__ out)
{
    __shared__ float wsm[HH][OUTC];
    int tid = threadIdx.x;
    for (int i = tid; i < HH * OUTC; i += 256) wsm[i >> 6][i & 63] = W[i];
    __syncthreads();
    int j = tid & 63;
    int rq = tid >> 6;
    size_t r0 = (size_t)blockIdx.x * 16;
    float bj = b[j];
    #pragma unroll
    for (int i = 0; i < 4; ++i) {
        size_t row = r0 + rq * 4 + i;
        const float* xr = x + row * HH;
        float o = bj;
        #pragma unroll 8
        for (int k = 0; k < HH; ++k) o += fmaxf(xr[k], 0.0f) * wsm[k][j];
        out[row * OUTC + j] = o;
    }
}

extern "C" void kernel_launch(void* const* d_in, const int* in_sizes, int n_in,
                              void* d_out, int out_size, void* d_ws, size_t ws_size,
                              hipStream_t stream) {
    const int*   x_protein  = (const int*)d_in[0];
    const int*   x_molecule = (const int*)d_in[1];
    const int*   x_reaction = (const int*)d_in[2];
    const int*   x_complex  = (const int*)d_in[3];
    const int*   ei         = (const int*)d_in[4];   // (8, 2, NEDGE)
    const float* emb_p      = (const float*)d_in[5];
    const float* emb_m      = (const float*)d_in[6];
    const float* emb_r      = (const float*)d_in[7];
    const float* emb_c      = (const float*)d_in[8];
    const float* Wl         = (const float*)d_in[9];  // (2,8,H,H)
    const float* bl         = (const float*)d_in[10]; // (2,8,H)
    const float* Wr         = (const float*)d_in[11]; // (2,8,H,H)
    const float* W_out      = (const float*)d_in[12];
    const float* b_out      = (const float*)d_in[13];
    float* out = (float*)d_out;

    const size_t NH = (size_t)NN * HH;
    float*  accbuf = (float*)d_ws;                 // 4*NH f32
    __half* xh     = (__half*)(accbuf + 4 * NH);   // 4*NH halfs
    __half* mh     = xh + 4 * NH;                  // NH halfs
    __half* Bth    = mh + NH;                      // 16*256*128 halfs
    int* rowptr_all = (int*)(Bth + (size_t)16 * 256 * 128);
    int* srcs_all   = rowptr_all + 8 * (NN + 1);
    int* cursor     = srcs_all + (size_t)8 * NEDGE;

    // type ids: 0=protein 1=molecule 2=reaction 3=complex
    static const int SRC[8] = {0, 1, 3, 0, 1, 2, 2, 3};
    static const int DST[8] = {2, 2, 2, 3, 3, 0, 1, 0};
    static const int ACCF[8] = {0, 1, 1, 0, 1, 0, 0, 1};  // 0 = first writer

    // ---- CSR per edge type (shared by both layers) ----
    for (int e = 0; e < 8; ++e) {
        const int* si = ei + ((size_t)e * 2 + 0) * NEDGE;
        const int* di = ei + ((size_t)e * 2 + 1) * NEDGE;
        int* rowptr = rowptr_all + (size_t)e * (NN + 1);
        int* srcs   = srcs_all + (size_t)e * NEDGE;
        hipMemsetAsync(cursor, 0, NN * sizeof(int), stream);
        hist_kernel<<<(NEDGE + 255) / 256, 256, 0, stream>>>(di, cursor);
        scan_block<<<1, 1024, 0, stream>>>(cursor, rowptr);
        fill_csr<<<(NEDGE + 255) / 256, 256, 0, stream>>>(si, di, cursor, srcs);
    }

    // ---- fused fp16 weights + initial fp16 features ----
    build_Bt<<<2048, 256, 0, stream>>>(Wl, Wr, Bth);
    gather_emb_h<<<4096, 256, 0, stream>>>(x_protein,  emb_p, xh + 0 * NH);
    gather_emb_h<<<4096, 256, 0, stream>>>(x_molecule, emb_m, xh + 1 * NH);
    gather_emb_h<<<4096, 256, 0, stream>>>(x_reaction, emb_r, xh + 2 * NH);
    gather_emb_h<<<4096, 256, 0, stream>>>(x_complex,  emb_c, xh + 3 * NH);

    for (int l = 0; l < 2; ++l) {
        if (l == 1)
            relu_f2h<<<16384, 256, 0, stream>>>(accbuf, xh, (int)NH);  // 4*NH/4 float4s
        for (int e = 0; e < 8; ++e) {
            int* rowptr = rowptr_all + (size_t)e * (NN + 1);
            int* srcs   = srcs_all + (size_t)e * NEDGE;
            if (l == 0 && (SRC[e] == 2 || SRC[e] == 3)) {
                const_mean_h<<<8192, 256, 0, stream>>>(rowptr,
                    (const uint*)(xh + (size_t)SRC[e] * NH), (uint*)mh);
            } else {
                csr_mean_h<<<8192, 256, 0, stream>>>(rowptr, srcs,
                    xh + (size_t)SRC[e] * NH, mh);
            }
            size_t le = (size_t)(l * 8 + e);
            gemm_mfma<<<256, 256, 0, stream>>>(mh, xh + (size_t)DST[e] * NH,
                Bth + le * 256 * 128, bl + le * HH,
                accbuf + (size_t)DST[e] * NH, ACCF[e]);
        }
    }
    out_gemm<<<2048, 256, 0, stream>>>(accbuf + 2 * NH, W_out, b_out, out);
}

// Round 4
// 808.498 us; speedup vs baseline: 17.4635x; 1.4421x over previous
//
#include <hip/hip_runtime.h>
#include <hip/hip_fp16.h>

#define NN 32768
#define NEDGE 400000
#define HH 128
#define OUTC 64

using f16x8 = __attribute__((ext_vector_type(8))) _Float16;
using f32x4 = __attribute__((ext_vector_type(4))) float;

// ---------------- gather all 4 types to fp16 ----------------
__global__ __launch_bounds__(256) void gather_all(
    const int* __restrict__ i0, const int* __restrict__ i1,
    const int* __restrict__ i2, const int* __restrict__ i3,
    const float* __restrict__ e0, const float* __restrict__ e1,
    const float* __restrict__ e2, const float* __restrict__ e3,
    __half* __restrict__ xh)
{
    int gid = blockIdx.x * 256 + threadIdx.x;   // 4 * 2^20 chunk-ids
    int t = gid >> 20;
    int r = (gid >> 5) & (NN - 1);
    int c = gid & 31;
    const int* idx; const float* emb;
    switch (t) {
      case 0: idx = i0; emb = e0; break;
      case 1: idx = i1; emb = e1; break;
      case 2: idx = i2; emb = e2; break;
      default: idx = i3; emb = e3; break;
    }
    float4 v = ((const float4*)(emb + (size_t)idx[r] * HH))[c];
    __half2 h0 = __floats2half2_rn(v.x, v.y);
    __half2 h1 = __floats2half2_rn(v.z, v.w);
    ((__half2*)xh)[(size_t)gid * 2]     = h0;
    ((__half2*)xh)[(size_t)gid * 2 + 1] = h1;
}

// ------------- fused weight Bt[le][n=128][k=256] fp16 (k<128: Wl, k>=128: Wr) -------------
__global__ __launch_bounds__(256) void build_Bt(const float* __restrict__ Wl,
    const float* __restrict__ Wr, __half* __restrict__ Bt)
{
    int gid = blockIdx.x * 256 + threadIdx.x;   // 16*128*256 = 524288
    if (gid >= 16 * 128 * 256) return;
    int le = gid >> 15;
    int n  = (gid >> 8) & 127;
    int k  = gid & 255;
    float v = (k < 128) ? Wl[(size_t)le * 16384 + (size_t)k * 128 + n]
                        : Wr[(size_t)le * 16384 + (size_t)(k - 128) * 128 + n];
    Bt[gid] = __float2half(v);
}

// ------------- head weight Bto[n=64][k=128] fp16 -------------
__global__ __launch_bounds__(256) void build_Bto(const float* __restrict__ W,
    __half* __restrict__ Bto)
{
    int gid = blockIdx.x * 256 + threadIdx.x;
    if (gid >= OUTC * HH) return;
    int n = gid >> 7, k = gid & 127;
    Bto[gid] = __float2half(W[(size_t)k * OUTC + n]);
}

// ---------------- CSR build (batched over 8 edge types) ----------------
__global__ __launch_bounds__(256) void hist_all(const int* __restrict__ ei,
    int* __restrict__ cnts_all)
{
    int e = blockIdx.y;
    int i = blockIdx.x * 256 + threadIdx.x;
    if (i >= NEDGE) return;
    const int* di = ei + ((size_t)e * 2 + 1) * NEDGE;
    atomicAdd(&cnts_all[(size_t)e * NN + di[i]], 1);
}

__global__ __launch_bounds__(1024) void scan_all(int* __restrict__ cnts_all,
    int* __restrict__ rowptr_all)
{
    int e = blockIdx.x;
    int* data   = cnts_all + (size_t)e * NN;
    int* rowptr = rowptr_all + (size_t)e * (NN + 1);
    __shared__ int part[1024];
    int t = threadIdx.x;
    int base = t * 32;
    int c[32];
    int run = 0;
    #pragma unroll
    for (int i = 0; i < 32; ++i) { int v = data[base + i]; c[i] = run; run += v; }
    part[t] = run;
    __syncthreads();
    for (int off = 1; off < 1024; off <<= 1) {
        int v = (t >= off) ? part[t - off] : 0;
        __syncthreads();
        part[t] += v;
        __syncthreads();
    }
    int excl = part[t] - run;
    #pragma unroll
    for (int i = 0; i < 32; ++i) {
        int b = excl + c[i];
        data[base + i]   = b;     // becomes fill cursor
        rowptr[base + i] = b;
    }
    if (t == 1023) rowptr[NN] = part[1023];
}

__global__ __launch_bounds__(256) void fill_all(const int* __restrict__ ei,
    int* __restrict__ cursor_all, int* __restrict__ srcs_all)
{
    int e = blockIdx.y;
    int i = blockIdx.x * 256 + threadIdx.x;
    if (i >= NEDGE) return;
    const int* si = ei + ((size_t)e * 2 + 0) * NEDGE;
    const int* di = ei + ((size_t)e * 2 + 1) * NEDGE;
    int p = atomicAdd(&cursor_all[(size_t)e * NN + di[i]], 1);
    srcs_all[(size_t)e * NEDGE + p] = si[i];
}

// ---------------- batched pull aggregation: all 8 edge types in one dispatch ----------------
__global__ __launch_bounds__(256) void csr_mean_all(
    const int* __restrict__ rowptr_all, const int* __restrict__ srcs_all,
    const __half* __restrict__ xh, __half* __restrict__ m_all, int layer0)
{
    constexpr int SRCc[8] = {0, 1, 3, 0, 1, 2, 2, 3};
    const size_t NH = (size_t)NN * HH;
    int e = blockIdx.y;
    int src = SRCc[e];
    const int* rowptr = rowptr_all + (size_t)e * (NN + 1);
    const int* srcs   = srcs_all + (size_t)e * NEDGE;
    const uint* xs = (const uint*)(xh + (size_t)src * NH);
    uint* m = (uint*)(m_all + (size_t)e * NH);
    int row  = (blockIdx.x * 256 + threadIdx.x) >> 6;  // one wave per dst row
    int lane = threadIdx.x & 63;
    int beg = rowptr[row], end = rowptr[row + 1];
    if (layer0 && src >= 2) {
        // layer-0 reaction/complex features are a broadcast row: mean == row0
        m[(size_t)row * 64 + lane] = (end > beg) ? xs[lane] : 0u;
        return;
    }
    float ax0 = 0.f, ay0 = 0.f, ax1 = 0.f, ay1 = 0.f;
    float ax2 = 0.f, ay2 = 0.f, ax3 = 0.f, ay3 = 0.f;
    int j = beg;
    for (; j + 4 <= end; j += 4) {
        int s0 = srcs[j], s1 = srcs[j + 1], s2 = srcs[j + 2], s3 = srcs[j + 3];
        uint v0 = xs[(size_t)s0 * 64 + lane];
        uint v1 = xs[(size_t)s1 * 64 + lane];
        uint v2 = xs[(size_t)s2 * 64 + lane];
        uint v3 = xs[(size_t)s3 * 64 + lane];
        float2 f0 = __half22float2(*(__half2*)&v0);
        float2 f1 = __half22float2(*(__half2*)&v1);
        float2 f2 = __half22float2(*(__half2*)&v2);
        float2 f3 = __half22float2(*(__half2*)&v3);
        ax0 += f0.x; ay0 += f0.y;  ax1 += f1.x; ay1 += f1.y;
        ax2 += f2.x; ay2 += f2.y;  ax3 += f3.x; ay3 += f3.y;
    }
    for (; j < end; ++j) {
        int s0 = srcs[j];
        uint v0 = xs[(size_t)s0 * 64 + lane];
        float2 f0 = __half22float2(*(__half2*)&v0);
        ax0 += f0.x; ay0 += f0.y;
    }
    float inv = 1.0f / fmaxf((float)(end - beg), 1.0f);
    __half2 h = __floats2half2_rn((ax0 + ax1 + ax2 + ax3) * inv,
                                  (ay0 + ay1 + ay2 + ay3) * inv);
    m[(size_t)row * 64 + lane] = *(uint*)&h;
}

// ------- per-layer fused GEMM: block = (dst d, 128 rows); loops contributing e,
//         racc += l2norm([m_e | x_d] @ Bt_e^T + bl_e); writes relu(racc) as fp16 -------
__global__ __launch_bounds__(256) void gemm_fused(
    const __half* __restrict__ m_all, const __half* __restrict__ xh,
    const __half* __restrict__ Bt, const float* __restrict__ bl,
    __half* __restrict__ xnext, int layer)
{
    constexpr int NCONc[4]   = {2, 1, 3, 2};
    constexpr int CONE[4][3] = {{5, 7, 0}, {6, 0, 0}, {0, 1, 2}, {3, 4, 0}};
    __shared__ __half As[128][40];   // 32-halfs k-slice + pad (80B rows, 16B aligned)
    __shared__ __half Bs[128][40];
    __shared__ __half Cs[128][136];  // epilogue transpose (272B rows, 16B aligned)
    const size_t NH = (size_t)NN * HH;
    int tid  = threadIdx.x;
    int lane = tid & 63;
    int wave = tid >> 6;
    int d  = blockIdx.x & 3;
    int rb = blockIdx.x >> 2;
    size_t r0 = (size_t)rb * 128;
    const __half* xd = xh + (size_t)d * NH;

    const int c15 = lane & 15;
    const int g   = lane >> 4;
    const int arow = wave * 32 + c15;
    const int kof  = g * 8;
    const int ra = tid >> 2, ca = tid & 3;   // load slot A: rows 0..63
    const int rb2 = 64 + ra;                 // rows 64..127

    f32x4 racc[2][8];
    #pragma unroll
    for (int mf = 0; mf < 2; ++mf)
        #pragma unroll
        for (int nf = 0; nf < 8; ++nf) racc[mf][nf] = (f32x4){0.f, 0.f, 0.f, 0.f};

    const int ncon = NCONc[d];
    for (int ci = 0; ci < ncon; ++ci) {
        int e  = CONE[d][ci];
        int le = layer * 8 + e;
        const __half* mh  = m_all + (size_t)e * NH;
        const __half* Bte = Bt + (size_t)le * 256 * 128;
        const float*  bias = bl + (size_t)le * HH;

        f32x4 acc[2][8];
        #pragma unroll
        for (int nf = 0; nf < 8; ++nf) {
            float bv = bias[c15 + nf * 16];
            acc[0][nf] = (f32x4){bv, bv, bv, bv};
            acc[1][nf] = acc[0][nf];
        }

        for (int ks = 0; ks < 8; ++ks) {
            int k0 = ks * 32;
            const __half* Asrc = (k0 < 128) ? (mh + k0) : (xd + (k0 - 128));
            __syncthreads();
            uint4 a0 = *(const uint4*)(Asrc + (r0 + ra)  * HH + ca * 8);
            uint4 a1 = *(const uint4*)(Asrc + (r0 + rb2) * HH + ca * 8);
            uint4 b0 = *(const uint4*)(Bte + (size_t)ra  * 256 + k0 + ca * 8);
            uint4 b1 = *(const uint4*)(Bte + (size_t)rb2 * 256 + k0 + ca * 8);
            *(uint4*)&As[ra][ca * 8]  = a0;
            *(uint4*)&As[rb2][ca * 8] = a1;
            *(uint4*)&Bs[ra][ca * 8]  = b0;
            *(uint4*)&Bs[rb2][ca * 8] = b1;
            __syncthreads();
            f16x8 af[2], bf[8];
            #pragma unroll
            for (int mf = 0; mf < 2; ++mf)
                af[mf] = *(const f16x8*)&As[arow + mf * 16][kof];
            #pragma unroll
            for (int nf = 0; nf < 8; ++nf)
                bf[nf] = *(const f16x8*)&Bs[nf * 16 + c15][kof];
            #pragma unroll
            for (int mf = 0; mf < 2; ++mf)
                #pragma unroll
                for (int nf = 0; nf < 8; ++nf)
                    acc[mf][nf] = __builtin_amdgcn_mfma_f32_16x16x32_f16(
                        af[mf], bf[nf], acc[mf][nf], 0, 0, 0);
        }

        // per-row l2 norm (cols live across the 16-lane group; rows = g*4+reg)
        #pragma unroll
        for (int mf = 0; mf < 2; ++mf) {
            #pragma unroll
            for (int r = 0; r < 4; ++r) {
                float s = 0.f;
                #pragma unroll
                for (int nf = 0; nf < 8; ++nf) { float v = acc[mf][nf][r]; s += v * v; }
                s += __shfl_xor(s, 1);
                s += __shfl_xor(s, 2);
                s += __shfl_xor(s, 4);
                s += __shfl_xor(s, 8);
                float scale = 1.0f / fmaxf(sqrtf(s), 1e-12f);
                #pragma unroll
                for (int nf = 0; nf < 8; ++nf)
                    racc[mf][nf][r] += acc[mf][nf][r] * scale;
            }
        }
    }

    // epilogue: relu -> fp16, LDS transpose, coalesced uint4 store
    #pragma unroll
    for (int mf = 0; mf < 2; ++mf)
        #pragma unroll
        for (int r = 0; r < 4; ++r)
            #pragma unroll
            for (int nf = 0; nf < 8; ++nf)
                Cs[wave * 32 + mf * 16 + g * 4 + r][nf * 16 + c15] =
                    __float2half(fmaxf(racc[mf][nf][r], 0.f));
    __syncthreads();
    __half* dst = xnext + (size_t)d * NH;
    #pragma unroll
    for (int i = 0; i < 8; ++i) {
        int s = tid + i * 256;         // 2048 chunks: 128 rows x 16 uint4
        int row = s >> 4, c = s & 15;
        *(uint4*)(dst + (r0 + row) * HH + c * 8) = *(const uint4*)&Cs[row][c * 8];
    }
}

// ---------------- head: out = x_reaction(fp16, relu'd) @ W_out + b_out ----------------
__global__ __launch_bounds__(256) void out_mfma(const __half* __restrict__ x,
    const __half* __restrict__ Bto, const float* __restrict__ b,
    float* __restrict__ out)
{
    __shared__ __half As[128][40];
    __shared__ __half Bs[64][40];
    int tid  = threadIdx.x;
    int lane = tid & 63;
    int wave = tid >> 6;
    const int c15 = lane & 15;
    const int g   = lane >> 4;
    size_t r0 = (size_t)blockIdx.x * 128;
    const int ra = tid >> 2, ca = tid & 3, rb2 = 64 + ra;

    f32x4 acc[2][4];
    #pragma unroll
    for (int nf = 0; nf < 4; ++nf) {
        float bv = b[c15 + nf * 16];
        acc[0][nf] = (f32x4){bv, bv, bv, bv};
        acc[1][nf] = acc[0][nf];
    }

    for (int ks = 0; ks < 4; ++ks) {
        int k0 = ks * 32;
        __syncthreads();
        uint4 a0 = *(const uint4*)(x + (r0 + ra)  * HH + k0 + ca * 8);
        uint4 a1 = *(const uint4*)(x + (r0 + rb2) * HH + k0 + ca * 8);
        uint4 b0 = *(const uint4*)(Bto + (size_t)(tid >> 2) * HH + k0 + (tid & 3) * 8);
        *(uint4*)&As[ra][ca * 8]  = a0;
        *(uint4*)&As[rb2][ca * 8] = a1;
        if (tid < 256) *(uint4*)&Bs[tid >> 2][(tid & 3) * 8] = b0;
        __syncthreads();
        f16x8 af[2], bf[4];
        #pragma unroll
        for (int mf = 0; mf < 2; ++mf)
            af[mf] = *(const f16x8*)&As[wave * 32 + c15 + mf * 16][g * 8];
        #pragma unroll
        for (int nf = 0; nf < 4; ++nf)
            bf[nf] = *(const f16x8*)&Bs[nf * 16 + c15][g * 8];
        #pragma unroll
        for (int mf = 0; mf < 2; ++mf)
            #pragma unroll
            for (int nf = 0; nf < 4; ++nf)
                acc[mf][nf] = __builtin_amdgcn_mfma_f32_16x16x32_f16(
                    af[mf], bf[nf], acc[mf][nf], 0, 0, 0);
    }

    #pragma unroll
    for (int mf = 0; mf < 2; ++mf)
        #pragma unroll
        for (int r = 0; r < 4; ++r) {
            size_t row = r0 + wave * 32 + mf * 16 + g * 4 + r;
            #pragma unroll
            for (int nf = 0; nf < 4; ++nf)
                out[row * OUTC + nf * 16 + c15] = acc[mf][nf][r];
        }
}

extern "C" void kernel_launch(void* const* d_in, const int* in_sizes, int n_in,
                              void* d_out, int out_size, void* d_ws, size_t ws_size,
                              hipStream_t stream) {
    const int*   x_protein  = (const int*)d_in[0];
    const int*   x_molecule = (const int*)d_in[1];
    const int*   x_reaction = (const int*)d_in[2];
    const int*   x_complex  = (const int*)d_in[3];
    const int*   ei         = (const int*)d_in[4];   // (8, 2, NEDGE)
    const float* emb_p      = (const float*)d_in[5];
    const float* emb_m      = (const float*)d_in[6];
    const float* emb_r      = (const float*)d_in[7];
    const float* emb_c      = (const float*)d_in[8];
    const float* Wl         = (const float*)d_in[9];  // (2,8,H,H)
    const float* bl         = (const float*)d_in[10]; // (2,8,H)
    const float* Wr         = (const float*)d_in[11]; // (2,8,H,H)
    const float* W_out      = (const float*)d_in[12];
    const float* b_out      = (const float*)d_in[13];
    float* out = (float*)d_out;

    const size_t NH = (size_t)NN * HH;
    __half* xh0   = (__half*)d_ws;                 // 4*NH
    __half* xh1   = xh0 + 4 * NH;                  // 4*NH
    __half* m_all = xh1 + 4 * NH;                  // 8*NH
    __half* Bt    = m_all + 8 * NH;                // 16*256*128
    __half* Bto   = Bt + (size_t)16 * 256 * 128;   // 64*128
    int* rowptr_all = (int*)(Bto + OUTC * HH);     // 8*(NN+1)
    int* srcs_all   = rowptr_all + 8 * (NN + 1);   // 8*NEDGE
    int* cnts_all   = srcs_all + (size_t)8 * NEDGE; // 8*NN (hist -> cursor)

    // ---- CSR build, batched ----
    hipMemsetAsync(cnts_all, 0, (size_t)8 * NN * sizeof(int), stream);
    dim3 eg((NEDGE + 255) / 256, 8);
    hist_all<<<eg, 256, 0, stream>>>(ei, cnts_all);
    scan_all<<<8, 1024, 0, stream>>>(cnts_all, rowptr_all);
    fill_all<<<eg, 256, 0, stream>>>(ei, cnts_all, srcs_all);

    // ---- weights + initial features ----
    build_Bt<<<2048, 256, 0, stream>>>(Wl, Wr, Bt);
    build_Bto<<<32, 256, 0, stream>>>(W_out, Bto);
    gather_all<<<16384, 256, 0, stream>>>(x_protein, x_molecule, x_reaction, x_complex,
                                          emb_p, emb_m, emb_r, emb_c, xh0);

    // ---- layer 0 ----
    csr_mean_all<<<dim3(8192, 8), 256, 0, stream>>>(rowptr_all, srcs_all, xh0, m_all, 1);
    gemm_fused<<<1024, 256, 0, stream>>>(m_all, xh0, Bt, bl, xh1, 0);
    // ---- layer 1 ----
    csr_mean_all<<<dim3(8192, 8), 256, 0, stream>>>(rowptr_all, srcs_all, xh1, m_all, 0);
    gemm_fused<<<1024, 256, 0, stream>>>(m_all, xh1, Bt, bl, xh0, 1);

    // ---- head (reaction = type 2) ----
    out_mfma<<<256, 256, 0, stream>>>(xh0 + 2 * NH, Bto, b_out, out);
}